// Round 8
// baseline (1236.540 us; speedup 1.0000x reference)
//
#include <hip/hip_runtime.h>
#include <cstdint>
#include <cstddef>

typedef __attribute__((ext_vector_type(8))) short short8;
typedef __attribute__((ext_vector_type(4))) float f32x4;

#define MFMA16(a, b, c) __builtin_amdgcn_mfma_f32_16x16x32_bf16((a), (b), (c), 0, 0, 0)
#define ALOADI(p)   __hip_atomic_load((p), __ATOMIC_RELAXED, __HIP_MEMORY_SCOPE_AGENT)
#define ALOADU64(p) __hip_atomic_load((p), __ATOMIC_RELAXED, __HIP_MEMORY_SCOPE_AGENT)
#define ASTOREU16(p, v) __hip_atomic_store((p), (v), __ATOMIC_RELAXED, __HIP_MEMORY_SCOPE_AGENT)

constexpr int kB = 512, kS = 256, kI = 12, kH = 256, kA = 9;
constexpr int kNS = 8;    // hidden slices per batch tile (32 h-units each)
constexpr int kNB = 32;   // batch tiles (16 rows each)
constexpr int kT  = 512;  // 8 waves
constexpr int LDH = 264;  // padded LDS stride (bf16) for 16x256 operand tiles
constexpr int LDT = 17;   // transpose scratch row stride (fp32, 16+1)
constexpr int kBH = kB * kH;
constexpr int FLS = 512;  // flag ints per btile: [0..255]=f0, [256..511]=f1
constexpr int kPubs = kNS * 8;  // 64 wave-publishes complete a flag

// d_out layout (floats): [logits 512*9][h0 512*256][h1 512*256][c0 512*256][c1 512*256]
constexpr int OUT_H = kB * kA;              // 4608
constexpr int OUT_C = OUT_H + 2 * kBH;      // 266752

__device__ __forceinline__ short f2bf(float f) {  // RTNE fp32 -> bf16 bits
  uint32_t u = __float_as_uint(f);
  u += 0x7fffu + ((u >> 16) & 1u);
  return (short)(u >> 16);
}
__device__ __forceinline__ float fast_sigmoid(float v) {
  return __builtin_amdgcn_rcpf(1.f + __expf(-v));
}
__device__ __forceinline__ float fast_tanh(float v) {
  return 2.f * __builtin_amdgcn_rcpf(1.f + __expf(-2.f * v)) - 1.f;
}

// Persistent fused scan, pipeline-skewed (phase p: layer0 step p, layer1 step p-1).
// R8: chain-latency attack on the R4 structure (best measured):
//  * wave's 16 B-cols = (gate=n16>>2, unit=n16&3) -> all 4 gates of 4 units per
//    wave -> gates->ew via WAVE-PRIVATE LDS transpose (no gL tile, no barrier).
//  * per-wave publish: own-store vmcnt(0) drain + lane0 flag add (count 64) —
//    h0(p) publishes before gates1/ew1/emb, which cover its IC propagation.
//  * ONE __syncthreads per phase; all phase-crossing LDS buffers are parity
//    double-buffered (gather/emb write [!par] while readers use [par]).
// Exchange = plain bf16 u16 relaxed agent stores (no tags — flags gate reads).
__global__ __launch_bounds__(kT, 2) void lstm_scan_kernel(
    const float* __restrict__ x,
    const float* __restrict__ W_emb, const float* __restrict__ b_emb,
    const float* __restrict__ w_ih0, const float* __restrict__ w_hh0,
    const float* __restrict__ b_ih0, const float* __restrict__ b_hh0,
    const float* __restrict__ w_ih1, const float* __restrict__ w_hh1,
    const float* __restrict__ b_ih1, const float* __restrict__ b_hh1,
    unsigned short* __restrict__ h0ex, unsigned short* __restrict__ h1ex,
    int* __restrict__ flags,
    float* __restrict__ dout)
{
  const int tid   = threadIdx.x;
  const int btile = blockIdx.x & (kNB - 1);  // bid%32 -> slices of a btile share an XCD
  const int slice = blockIdx.x >> 5;
  const int b0    = btile * 16;
  const int lane  = tid & 63;
  const int wave  = tid >> 6;                // owns units [slice*32 + wave*4, +4), all 4 gates
  const int n16   = lane & 15;
  const int quad  = lane >> 4;

  __shared__ short emb2[2][16 * LDH];  // emb(p) parity-buffered
  __shared__ short hA2[2][16 * LDH];   // h0(p-1)
  __shared__ short hB2[2][16 * LDH];   // h1(p-2)
  __shared__ float scr[8 * 16 * LDT];  // per-wave gate transpose scratch (272 f32 each)

  for (int i = tid; i < 16 * LDH; i += kT) { hA2[0][i] = 0; hB2[0][i] = 0; }

  // Weight B-fragments: slot n16 = g*4 + j  ->  weight row gcol = g*kH + slice*32 + wave*4 + j.
  // B-frag: lane(n16, quad) holds B[k=quad*8+jj][n16] (weights [4H,H] row-major).
  const float* Wm[4] = { w_ih0, w_hh0, w_ih1, w_hh1 };
  short8 wB[4][8];
  {
    const int gcol = (n16 >> 2) * kH + slice * 32 + wave * 4 + (n16 & 3);
#pragma unroll
    for (int mat = 0; mat < 4; ++mat) {
      const float* wp = Wm[mat] + (size_t)gcol * kH;
#pragma unroll
      for (int kk = 0; kk < 8; ++kk) {
        const float* p = wp + kk * 32 + quad * 8;
        const float4 f0 = *(const float4*)p;
        const float4 f1 = *(const float4*)(p + 4);
        short8 v;
        v[0] = f2bf(f0.x); v[1] = f2bf(f0.y); v[2] = f2bf(f0.z); v[3] = f2bf(f0.w);
        v[4] = f2bf(f1.x); v[5] = f2bf(f1.y); v[6] = f2bf(f1.z); v[7] = f2bf(f1.w);
        wB[mat][kk] = v;
      }
    }
  }
  // Embedding weights (K=12 zero-padded to 32). Wave computes emb cols [wave*32, +32).
  short8 wE[2];
  float bembv[2];
#pragma unroll
  for (int i = 0; i < 2; ++i) {
    const int col = wave * 32 + i * 16 + n16;
    short8 v;
#pragma unroll
    for (int j = 0; j < 8; ++j) {
      const int k = quad * 8 + j;
      v[j] = (k < kI) ? f2bf(W_emb[col * kI + k]) : (short)0;
    }
    wE[i] = v;
    bembv[i] = b_emb[col];
  }
  // ew lane mapping (post-transpose): lane -> (row, unit).
  const int row_ew = quad * 4 + (n16 >> 2);
  const int j_ew   = n16 & 3;
  const int ucol   = slice * 32 + wave * 4 + j_ew;
  const int grow   = b0 + row_ew;
  float bi0[4], bi1[4];
#pragma unroll
  for (int g = 0; g < 4; ++g) {
    bi0[g] = b_ih0[g * kH + ucol] + b_hh0[g * kH + ucol];
    bi1[g] = b_ih1[g * kH + ucol] + b_hh1[g * kH + ucol];
  }
  float c0v = 0.f, c1v = 0.f;
  float* const sw = scr + wave * (16 * LDT);

  // -------- prologue: emb(0) -> emb2[0] from direct global x loads --------
  {
    const float* xr = x + (size_t)(b0 + n16) * kS * kI;  // t = 0
    short8 xa;
#pragma unroll
    for (int j = 0; j < 8; ++j) {
      const int k = quad * 8 + j;
      xa[j] = (k < kI) ? f2bf(xr[k]) : (short)0;
    }
#pragma unroll
    for (int i = 0; i < 2; ++i) {
      f32x4 z = {0.f, 0.f, 0.f, 0.f};
      f32x4 e = MFMA16(xa, wE[i], z);
      const int col = wave * 32 + i * 16 + n16;
#pragma unroll
      for (int r = 0; r < 4; ++r) {
        float v = e[r] + bembv[i];
        v = v > 0.f ? v : 0.f;
        emb2[0][(quad * 4 + r) * LDH + col] = f2bf(v);
      }
    }
  }
  __syncthreads();

  int* const f0 = flags + btile * FLS;
  int* const f1 = f0 + 256;

  for (int p = 0; p <= kS; ++p) {
    const int rpar  = p & 1;        // read parity (emb(p), h0(p-1), h1(p-2))
    const int wpar  = rpar ^ 1;     // write parity for next phase's LDS buffers
    const int h1par = (p + 1) & 1;  // global-slot parity of h1(p-1)
    const short* embL = emb2[rpar];
    const short* hA   = hA2[rpar];
    const short* hB   = hB2[rpar];

    // S0: cache hA fragments (used by gates0 AND gates1)
    short8 haf[8];
#pragma unroll
    for (int kk = 0; kk < 8; ++kk)
      haf[kk] = *(const short8*)&hA[n16 * LDH + kk * 32 + quad * 8];

    // ---- S1: gates0(p) = emb(p)@w_ih0 + h0(p-1)@w_hh0 (16 MFMAs) ----
    if (p < kS) {
      f32x4 a0 = {0.f, 0.f, 0.f, 0.f};
#pragma unroll
      for (int kk = 0; kk < 8; ++kk) {
        const short8 e = *(const short8*)&embL[n16 * LDH + kk * 32 + quad * 8];
        a0 = MFMA16(e, wB[0][kk], a0);
      }
#pragma unroll
      for (int kk = 0; kk < 8; ++kk) a0 = MFMA16(haf[kk], wB[1][kk], a0);
      // S2: wave-private transpose: (lane n16=g*4+j, reg r) -> [row=4q+r][g*4+j]
#pragma unroll
      for (int r = 0; r < 4; ++r) sw[(quad * 4 + r) * LDT + n16] = a0[r];
      // S3: ew0 (lane owns (row_ew, unit j_ew); compiler inserts lgkm waits)
      const float iv = sw[row_ew * LDT +      j_ew] + bi0[0];
      const float fv = sw[row_ew * LDT +  4 + j_ew] + bi0[1];
      const float gv = sw[row_ew * LDT +  8 + j_ew] + bi0[2];
      const float ov = sw[row_ew * LDT + 12 + j_ew] + bi0[3];
      const float c = fast_sigmoid(fv) * c0v + fast_sigmoid(iv) * fast_tanh(gv);
      c0v = c;
      const float h = fast_sigmoid(ov) * fast_tanh(c);
      ASTOREU16(&h0ex[(size_t)rpar * kBH + (size_t)grow * kH + ucol],
                (unsigned short)f2bf(h));
      if (p == kS - 1) {
        dout[OUT_H + (size_t)grow * kH + ucol] = h;
        dout[OUT_C + (size_t)grow * kH + ucol] = c;
      }
      // S4: per-wave publish — drain own stores, then lane0 bumps f0[p]
      __builtin_amdgcn_sched_barrier(0);
      __builtin_amdgcn_s_waitcnt(0x0F70);  // vmcnt(0), lgkm/exp unconstrained
      __builtin_amdgcn_sched_barrier(0);
      if (lane == 0)
        __hip_atomic_fetch_add(f0 + p, 1, __ATOMIC_RELAXED, __HIP_MEMORY_SCOPE_AGENT);
    }

    // ---- S5/S6: gates1(p-1) = y0@w_ih1 + h1(p-2)@w_hh1, ew1 ----
    if (p >= 1) {
      f32x4 a1 = {0.f, 0.f, 0.f, 0.f};
#pragma unroll
      for (int kk = 0; kk < 8; ++kk) a1 = MFMA16(haf[kk], wB[2][kk], a1);
#pragma unroll
      for (int kk = 0; kk < 8; ++kk) {
        const short8 hb = *(const short8*)&hB[n16 * LDH + kk * 32 + quad * 8];
        a1 = MFMA16(hb, wB[3][kk], a1);
      }
#pragma unroll
      for (int r = 0; r < 4; ++r) sw[(quad * 4 + r) * LDT + n16] = a1[r];
      const float iv = sw[row_ew * LDT +      j_ew] + bi1[0];
      const float fv = sw[row_ew * LDT +  4 + j_ew] + bi1[1];
      const float gv = sw[row_ew * LDT +  8 + j_ew] + bi1[2];
      const float ov = sw[row_ew * LDT + 12 + j_ew] + bi1[3];
      const float c = fast_sigmoid(fv) * c1v + fast_sigmoid(iv) * fast_tanh(gv);
      c1v = c;
      const float h = fast_sigmoid(ov) * fast_tanh(c);
      if (p < kS) {
        ASTOREU16(&h1ex[(size_t)h1par * kBH + (size_t)grow * kH + ucol],
                  (unsigned short)f2bf(h));
      } else {  // p == kS: final h1/c1 outputs only
        dout[OUT_H + kBH + (size_t)grow * kH + ucol] = h;
        dout[OUT_C + kBH + (size_t)grow * kH + ucol] = c;
      }
    } else {  // p == 0: publish h1(-1) = 0 (consumed by phase 0's gather)
      ASTOREU16(&h1ex[(size_t)h1par * kBH + (size_t)grow * kH + ucol], (unsigned short)0);
    }
    if (p < kS) {
      __builtin_amdgcn_sched_barrier(0);
      __builtin_amdgcn_s_waitcnt(0x0F70);
      __builtin_amdgcn_sched_barrier(0);
      if (lane == 0)
        __hip_atomic_fetch_add(f1 + p, 1, __ATOMIC_RELAXED, __HIP_MEMORY_SCOPE_AGENT);
    }

    // ---- S8: emb(p+1) -> emb2[wpar] (covers flag/data propagation) ----
    if (p + 1 < kS) {
      const float* xr = x + ((size_t)(b0 + n16) * kS + (p + 1)) * kI;
      short8 xa;
#pragma unroll
      for (int j = 0; j < 8; ++j) {
        const int k = quad * 8 + j;
        xa[j] = (k < kI) ? f2bf(xr[k]) : (short)0;
      }
#pragma unroll
      for (int i = 0; i < 2; ++i) {
        f32x4 z = {0.f, 0.f, 0.f, 0.f};
        f32x4 e = MFMA16(xa, wE[i], z);
        const int col = wave * 32 + i * 16 + n16;
#pragma unroll
        for (int r = 0; r < 4; ++r) {
          float v = e[r] + bembv[i];
          v = v > 0.f ? v : 0.f;
          emb2[wpar][(quad * 4 + r) * LDH + col] = f2bf(v);
        }
      }
    }

    // ---- S9: spin (cheap single-word polls), S10: gather, S11: one barrier ----
    if (p < kS) {
      while (ALOADI(f0 + p) < kPubs) __builtin_amdgcn_s_sleep(1);
      while (ALOADI(f1 + p) < kPubs) __builtin_amdgcn_s_sleep(1);
      {
        const int rr = tid >> 5;
        const int cc = (tid & 31) * 8;
        const uint64_t* s0 = (const uint64_t*)&h0ex[(size_t)rpar * kBH + (size_t)(b0 + rr) * kH + cc];
        const uint64_t* s1 = (const uint64_t*)&h1ex[(size_t)h1par * kBH + (size_t)(b0 + rr) * kH + cc];
        uint64_t va0 = ALOADU64(s0 + 0);
        uint64_t va1 = ALOADU64(s0 + 1);
        uint64_t vb0 = ALOADU64(s1 + 0);
        uint64_t vb1 = ALOADU64(s1 + 1);
        uint64_t* dA = (uint64_t*)&hA2[wpar][rr * LDH + cc];
        uint64_t* dB = (uint64_t*)&hB2[wpar][rr * LDH + cc];
        dA[0] = va0; dA[1] = va1;
        dB[0] = vb0; dB[1] = vb1;
      }
      __syncthreads();  // the ONLY barrier: [wpar] buffers ready for next phase
    }
  }
}

// LayerNorm + MLP head, exact fp32. One wave per batch row.
__global__ __launch_bounds__(64) void head_kernel(
    const float* __restrict__ h1last, const float* __restrict__ mask,
    const float* __restrict__ ln_g, const float* __restrict__ ln_b,
    const float* __restrict__ w1, const float* __restrict__ b1,
    const float* __restrict__ w2, const float* __restrict__ b2,
    float* __restrict__ out)
{
  const int r = blockIdx.x;
  const int lane = threadIdx.x;
  __shared__ float ns[kH];
  __shared__ float hd[32];
  const float4 v = *(const float4*)&h1last[r * kH + lane * 4];
  float vv[4] = {v.x, v.y, v.z, v.w};
  float s = vv[0] + vv[1] + vv[2] + vv[3];
#pragma unroll
  for (int off = 32; off > 0; off >>= 1) s += __shfl_xor(s, off, 64);
  const float mean = s * (1.f / kH);
  float q = 0.f;
#pragma unroll
  for (int j = 0; j < 4; ++j) { const float d = vv[j] - mean; q += d * d; }
#pragma unroll
  for (int off = 32; off > 0; off >>= 1) q += __shfl_xor(q, off, 64);
  const float rstd = rsqrtf(q * (1.f / kH) + 1e-5f);
#pragma unroll
  for (int j = 0; j < 4; ++j) {
    const int c = lane * 4 + j;
    ns[c] = (vv[j] - mean) * rstd * ln_g[c] + ln_b[c];
  }
  __syncthreads();
  if (lane < 32) {
    float a = b1[lane];
    const float* wr = w1 + lane * kH;
    for (int k = 0; k < kH; ++k) a += ns[k] * wr[k];
    hd[lane] = a > 0.f ? a : 0.f;
  }
  __syncthreads();
  if (lane < kA) {
    float a = b2[lane];
    const float* wr = w2 + lane * 32;
#pragma unroll
    for (int k = 0; k < 32; ++k) a += hd[k] * wr[k];
    a += (1.f - mask[r * kA + lane]) * (-1e9f);
    out[r * kA + lane] = a;
  }
}

extern "C" void kernel_launch(void* const* d_in, const int* in_sizes, int n_in,
                              void* d_out, int out_size, void* d_ws, size_t ws_size,
                              hipStream_t stream)
{
  (void)in_sizes; (void)n_in; (void)out_size; (void)ws_size;
  const float* x     = (const float*)d_in[0];
  const float* mask  = (const float*)d_in[1];
  const float* W_emb = (const float*)d_in[2];
  const float* b_emb = (const float*)d_in[3];
  const float* w_ih0 = (const float*)d_in[4];
  const float* w_hh0 = (const float*)d_in[5];
  const float* b_ih0 = (const float*)d_in[6];
  const float* b_hh0 = (const float*)d_in[7];
  const float* w_ih1 = (const float*)d_in[8];
  const float* w_hh1 = (const float*)d_in[9];
  const float* b_ih1 = (const float*)d_in[10];
  const float* b_hh1 = (const float*)d_in[11];
  const float* ln_g  = (const float*)d_in[12];
  const float* ln_b  = (const float*)d_in[13];
  const float* w1    = (const float*)d_in[14];
  const float* b1    = (const float*)d_in[15];
  const float* w2    = (const float*)d_in[16];
  const float* b2    = (const float*)d_in[17];
  float* out = (float*)d_out;

  // ws: h0ex u16[2][512][256] | h1ex u16[2][512][256] | flags int[32][512]
  unsigned short* h0ex = (unsigned short*)d_ws;
  unsigned short* h1ex = h0ex + 2 * kBH;
  int* flags = (int*)(h1ex + 2 * kBH);
  const size_t flag_bytes = (size_t)kNB * FLS * sizeof(int);  // 64 KiB

  // Flags must start at 0 (monotonic counters). Exchange buffers need no init:
  // flag protocol gates every read, and h1(-1)=0 is explicitly published at p=0.
  hipMemsetAsync(flags, 0, flag_bytes, stream);

  lstm_scan_kernel<<<dim3(kNB * kNS), dim3(kT), 0, stream>>>(
      x, W_emb, b_emb, w_ih0, w_hh0, b_ih0, b_hh0, w_ih1, w_hh1, b_ih1, b_hh1,
      h0ex, h1ex, flags, out);

  head_kernel<<<dim3(kB), dim3(64), 0, stream>>>(
      out + OUT_H + kBH, mask, ln_g, ln_b, w1, b1, w2, b2, out);
}